// Round 11
// baseline (4471.334 us; speedup 1.0000x reference)
//
#include <hip/hip_runtime.h>
#include <hip/hip_bf16.h>
#include <math.h>

#define S_DIM 128
#define H_DIM 256
#define A_DIM 8
#define T_STEPS 16
#define BT 4                // batch elems per iteration
#define EPS_BAND 2e-4f

typedef __attribute__((ext_vector_type(8))) short short8;
typedef __attribute__((ext_vector_type(8))) unsigned short ushort8;
typedef __attribute__((ext_vector_type(4))) float f32x4;

__device__ inline unsigned short f32_to_bf16_rn(float f) {
    unsigned int u = __float_as_uint(f);
    return (unsigned short)((u + 0x7FFFu + ((u >> 16) & 1u)) >> 16);
}
__device__ inline float bf16_bits_to_f32(unsigned short b) {
    return __uint_as_float(((unsigned int)b) << 16);
}

// exact f64 h1 + 16-step L1 recursion -> 16-bit spike pattern per (b,n).
// thread handles neuron n1 for 2 batch elems (bh selects which pair).
__device__ __forceinline__ void make_pat2(
    const float* __restrict__ state, const float* __restrict__ W1,
    double b1d, int n1, int bh, long bset, unsigned short* __restrict__ patdst)
{
    double acc[2] = {0.0, 0.0};
    const float4* w1p = reinterpret_cast<const float4*>(W1 + n1 * S_DIM);
    const float4* sp  = reinterpret_cast<const float4*>(state + (bset * BT + bh * 2) * S_DIM);
    #pragma unroll 4
    for (int kq = 0; kq < 32; ++kq) {
        const float4 w4 = w1p[kq];
        const double wd0 = (double)w4.x, wd1 = (double)w4.y;
        const double wd2 = (double)w4.z, wd3 = (double)w4.w;
        #pragma unroll
        for (int b2i = 0; b2i < 2; ++b2i) {
            const float4 s4 = sp[b2i * 32 + kq];
            double a = acc[b2i];
            a = fma(wd0, (double)s4.x, a);
            a = fma(wd1, (double)s4.y, a);
            a = fma(wd2, (double)s4.z, a);
            a = fma(wd3, (double)s4.w, a);
            acc[b2i] = a;
        }
    }
    #pragma unroll
    for (int b2i = 0; b2i < 2; ++b2i) {
        const double h1 = acc[b2i] + b1d;
        double v = 0.0;
        unsigned int p = 0;
        #pragma unroll
        for (int t = 0; t < T_STEPS; ++t) {
            v = v + (h1 - v) * 0.5;
            if (v >= 1.0) { p |= (1u << t); v = 0.0; }
        }
        patdst[(bh * 2 + b2i) * 256 + n1] = (unsigned short)p;
    }
}

// ====== persistent main: 1024 blocks x 32 iters of 4 batch elems =============
// 8 waves; wave w owns neurons w*32..w*32+31 (W2 hi/mid bf16 frags in regs).
// Per iter: A-tiles [16t x 256j] frag-major (32 KB) -> barrier -> 2 pair-GEMMs
// with in-register shuffle-carry v2 recursion (no LDS transpose) -> f64
// patterns for next iter -> barrier -> epilogue. ~47.5 KB LDS -> 3 blocks/CU.
__global__ __launch_bounds__(512, 6)
void snn_pers(const float* __restrict__ state,
              const float* __restrict__ W1, const float* __restrict__ b1,
              const float* __restrict__ W2, const float* __restrict__ b2,
              const float* __restrict__ W3, const float* __restrict__ b3,
              float* __restrict__ out,
              unsigned int* __restrict__ gcount, unsigned int* __restrict__ glist,
              unsigned int listcap, int nIter)
{
    __shared__ unsigned short atile[BT * 4096];   // 32 KB  A-tiles (frag-major)
    __shared__ unsigned short pat[BT * 256];      // 2 KB   L1 patterns
    __shared__ float st_u[BT * 260];              // 4.2 KB u vectors
    __shared__ float w3s[A_DIM * 260];            // 8.3 KB W3 staged
    __shared__ float red3[8][BT * A_DIM];         // 1 KB   epilogue partials
    __shared__ unsigned int flagw;

    const int tid = threadIdx.x;
    const int l = tid & 63, w = tid >> 6;
    const int cl = l & 15, c8 = l >> 4;

    if (tid == 0) flagw = 0;

    // ---- stage W3 [8][260] ----
    {
        const int a = tid >> 6, c = tid & 63;
        const float4 v = reinterpret_cast<const float4*>(W3)[tid];
        *reinterpret_cast<float4*>(&w3s[a * 260 + c * 4]) = v;
    }

    // ---- W2 hi/mid bf16 fragments, register-resident (built once) ----
    short8 bhi[2][8], bmid[2][8];
    #pragma unroll
    for (int nt = 0; nt < 2; ++nt) {
        const int n = w * 32 + nt * 16 + cl;
        #pragma unroll
        for (int ks = 0; ks < 8; ++ks) {
            const float* src = W2 + n * H_DIM + ks * 32 + c8 * 8;
            const float4 a0 = *reinterpret_cast<const float4*>(src);
            const float4 a1 = *reinterpret_cast<const float4*>(src + 4);
            const float wv[8] = {a0.x, a0.y, a0.z, a0.w, a1.x, a1.y, a1.z, a1.w};
            short8 hi8, mi8;
            #pragma unroll
            for (int e = 0; e < 8; ++e) {
                const unsigned short hb = f32_to_bf16_rn(wv[e]);
                const float rem = wv[e] - bf16_bits_to_f32(hb);
                hi8[e] = (short)hb;
                mi8[e] = (short)f32_to_bf16_rn(rem);
            }
            bhi[nt][ks] = hi8;
            bmid[nt][ks] = mi8;
        }
    }
    const float b2lo = b2[w * 32 + cl];
    const float b2hi = b2[w * 32 + 16 + cl];
    const int n1 = tid & 255, bh = tid >> 8;
    const double b1d = (double)b1[n1];

    const long bsetBase = (long)blockIdx.x * nIter;

    make_pat2(state, W1, b1d, n1, bh, bsetBase, pat);
    __syncthreads();

    #pragma unroll 1
    for (int it = 0; it < nIter; ++it) {
        const long b0 = (bsetBase + it) * BT;

        // ---- build A-tiles (reads pat; WAR vs make_pat separated by [A]) ----
        {
            const int jb = w * 32 + c8 * 8;
            #pragma unroll
            for (int b = 0; b < BT; ++b) {
                const ushort8 p8 = *reinterpret_cast<const ushort8*>(&pat[b * 256 + jb]);
                short8 af;
                #pragma unroll
                for (int e = 0; e < 8; ++e)
                    af[e] = (short)((((unsigned int)p8[e] >> cl) & 1u) ? 0x3F80 : 0);
                *reinterpret_cast<short8*>(&atile[b * 4096 + tid * 8]) = af;
            }
        }
        __syncthreads();   // [A] tiles ready; pat reads complete

        // ---- 2 batch-pairs: GEMM + shuffle-carry recursion (no barriers) ----
        #pragma unroll 1
        for (int p2 = 0; p2 < 2; ++p2) {
            f32x4 c00 = {0,0,0,0}, c01 = {0,0,0,0}, c10 = {0,0,0,0}, c11 = {0,0,0,0};
            #pragma unroll
            for (int ks = 0; ks < 8; ++ks) {
                const short8 af0 = *reinterpret_cast<const short8*>(
                    &atile[(2 * p2) * 4096 + (ks * 64 + l) * 8]);
                const short8 af1 = *reinterpret_cast<const short8*>(
                    &atile[(2 * p2 + 1) * 4096 + (ks * 64 + l) * 8]);
                c00 = __builtin_amdgcn_mfma_f32_16x16x32_bf16(af0, bhi[0][ks],  c00, 0, 0, 0);
                c00 = __builtin_amdgcn_mfma_f32_16x16x32_bf16(af0, bmid[0][ks], c00, 0, 0, 0);
                c01 = __builtin_amdgcn_mfma_f32_16x16x32_bf16(af0, bhi[1][ks],  c01, 0, 0, 0);
                c01 = __builtin_amdgcn_mfma_f32_16x16x32_bf16(af0, bmid[1][ks], c01, 0, 0, 0);
                c10 = __builtin_amdgcn_mfma_f32_16x16x32_bf16(af1, bhi[0][ks],  c10, 0, 0, 0);
                c10 = __builtin_amdgcn_mfma_f32_16x16x32_bf16(af1, bmid[0][ks], c10, 0, 0, 0);
                c11 = __builtin_amdgcn_mfma_f32_16x16x32_bf16(af1, bhi[1][ks],  c11, 0, 0, 0);
                c11 = __builtin_amdgcn_mfma_f32_16x16x32_bf16(af1, bmid[1][ks], c11, 0, 0, 0);
            }

            // shuffle-carry pipelined recursion over C fragments.
            // chain (f,c): f=0..3 -> (b = 2p2+(f>>1), n = w*32+(f&1)*16+c).
            // t=4q+r lives in lane 16q+c, frag f, reg r. stage s: quarter q
            // processes frag f=s-q; carry (v2,m,vmin) flows lane q-1 -> q.
            {
                const int q = c8;
                float pv2 = 0.0f, pvm = 1e9f;
                unsigned int pm = 0u;
                unsigned int fm[4];
                float fvm[4];
                #pragma unroll
                for (int s = 0; s < 7; ++s) {
                    float rv2, rvm;
                    unsigned int rm;
                    if (s == 0) { rv2 = 0.0f; rm = 0u; rvm = 1e9f; }
                    else {
                        rv2 = __shfl_up(pv2, 16, 64);
                        rm  = __shfl_up(pm, 16, 64);
                        rvm = __shfl_up(pvm, 16, 64);
                        if (q == 0) { rv2 = 0.0f; rm = 0u; rvm = 1e9f; }
                    }
                    const int f = s - q;
                    const int fc = (f < 0) ? 0 : (f > 3 ? 3 : f);
                    const f32x4 av = (fc == 0) ? c00 : (fc == 1) ? c01
                                   : (fc == 2) ? c10 : c11;
                    const float b2f = ((fc & 1) != 0) ? b2hi : b2lo;
                    float v2 = rv2, vm = rvm;
                    unsigned int m = rm;
                    #pragma unroll
                    for (int r = 0; r < 4; ++r) {
                        const float v = (v2 + (av[r] + b2f)) * 0.5f;
                        vm = fminf(vm, fabsf(v - 1.0f));
                        const bool sp = v >= 1.0f;
                        v2 = sp ? 0.0f : v;
                        m |= (sp ? 1u : 0u) << (4 * q + r);
                    }
                    pv2 = v2; pm = m; pvm = vm;
                    if (s >= 3) {
                        if (q == 3) { fm[s - 3] = m; fvm[s - 3] = vm; }
                    }
                }
                if (q == 3) {
                    #pragma unroll
                    for (int f = 0; f < 4; ++f) {
                        const int b = 2 * p2 + (f >> 1);
                        const int n = w * 32 + (f & 1) * 16 + cl;
                        st_u[b * 260 + n] = (float)fm[f] * 0x1p-16f;
                        if (fvm[f] < EPS_BAND) atomicOr(&flagw, 1u << b);
                    }
                }
            }
        }

        // ---- patterns for next iter (f64; overlaps other waves' MFMA) ----
        if (it + 1 < nIter)
            make_pat2(state, W1, b1d, n1, bh, bsetBase + it + 1, pat);

        __syncthreads();   // [B] st_u + flags + next-pat complete

        const unsigned int flcopy = (tid < BT) ? flagw : 0u;

        // ---- epilogue: out = tanh(u @ W3^T + b3*(1-2^-16)) ----
        if (tid < 256) {
            const int task = tid & 31, chunk = tid >> 5;
            const int b = task >> 3, a = task & 7;
            const int j0 = chunk * 32;
            float s0 = 0, s1v = 0, s2v = 0, s3 = 0;
            #pragma unroll
            for (int qq = 0; qq < 8; ++qq) {
                const float4 uv = *reinterpret_cast<const float4*>(&st_u[b * 260 + j0 + qq * 4]);
                const float4 wv = *reinterpret_cast<const float4*>(&w3s[a * 260 + j0 + qq * 4]);
                s0 = fmaf(uv.x, wv.x, s0);
                s1v = fmaf(uv.y, wv.y, s1v);
                s2v = fmaf(uv.z, wv.z, s2v);
                s3 = fmaf(uv.w, wv.w, s3);
            }
            red3[chunk][task] = (s0 + s1v) + (s2v + s3);
        }
        __syncthreads();   // [C]

        if (tid < BT * A_DIM) {
            const int a = tid & 7;
            const float h = ((red3[0][tid] + red3[1][tid]) + (red3[2][tid] + red3[3][tid]))
                          + ((red3[4][tid] + red3[5][tid]) + (red3[6][tid] + red3[7][tid]))
                          + b3[a] * (1.0f - 0x1p-16f);
            out[b0 * A_DIM + tid] = tanhf(h);
        }
        if (tid < BT && ((flcopy >> tid) & 1u)) {
            const unsigned int idx = atomicAdd(gcount, 1u);
            if (idx < listcap) glist[idx] = (unsigned int)(b0 + tid);
        }
        if (tid == 0) flagw = 0;   // next atomics are after barrier [A]
    }
}

// ================ fixup: exact f64 re-sim of flagged elems (validated) =======
__global__ __launch_bounds__(512, 2)
void snn_fix(const float* __restrict__ state,
             const float* __restrict__ W1, const float* __restrict__ b1,
             const float* __restrict__ W2, const float* __restrict__ b2,
             const float* __restrict__ W3, const float* __restrict__ b3,
             float* __restrict__ out,
             const unsigned int* __restrict__ gcount,
             const unsigned int* __restrict__ glist,
             unsigned int listcap)
{
    __shared__ float  s1s[H_DIM];
    __shared__ double redh[H_DIM];
    __shared__ double uu[H_DIM];

    const int tid = threadIdx.x;
    const int n = tid & 255;
    const int kh = tid >> 8;
    unsigned int cnt = *gcount;
    if (cnt > listcap) cnt = listcap;
    if (cnt == 0) return;

    float4 w2f[32];
    #pragma unroll
    for (int q = 0; q < 32; ++q)
        w2f[q] = reinterpret_cast<const float4*>(W2 + n * H_DIM + kh * 128)[q];

    const double b1d = (double)b1[n];
    const double b2d = (double)b2[n];

    for (unsigned int i = blockIdx.x; i < cnt; i += gridDim.x) {
        const long be = (long)glist[i];

        double hp = 0.0;
        {
            const float* w1p = W1 + n * S_DIM + kh * 64;
            const float* stp = state + be * S_DIM + kh * 64;
            #pragma unroll
            for (int kq = 0; kq < 16; ++kq) {
                const float4 w4 = reinterpret_cast<const float4*>(w1p)[kq];
                const float4 s4 = reinterpret_cast<const float4*>(stp)[kq];
                hp = fma((double)w4.x, (double)s4.x, hp);
                hp = fma((double)w4.y, (double)s4.y, hp);
                hp = fma((double)w4.z, (double)s4.z, hp);
                hp = fma((double)w4.w, (double)s4.w, hp);
            }
        }
        if (kh) redh[n] = hp;
        __syncthreads();
        double h1 = 0.0, v1 = 0.0, v2 = 0.0, un = 0.0;
        if (!kh) h1 = hp + redh[n] + b1d;
        double ct = 0x1p-16;

        for (int t = 0; t < T_STEPS; ++t) {
            if (!kh) {
                v1 = v1 + (h1 - v1) * 0.5;
                const bool sp = (v1 >= 1.0);
                v1 = sp ? 0.0 : v1;
                s1s[n] = sp ? 1.0f : 0.0f;
            }
            __syncthreads();
            double h2p = 0.0;
            #pragma unroll
            for (int q = 0; q < 32; ++q) {
                const float4 w4 = w2f[q];
                const float4 s4 = *reinterpret_cast<const float4*>(&s1s[kh * 128 + q * 4]);
                h2p = fma((double)w4.x, (double)s4.x, h2p);
                h2p = fma((double)w4.y, (double)s4.y, h2p);
                h2p = fma((double)w4.z, (double)s4.z, h2p);
                h2p = fma((double)w4.w, (double)s4.w, h2p);
            }
            __syncthreads();
            if (kh) redh[n] = h2p;
            __syncthreads();
            if (!kh) {
                const double h2 = h2p + redh[n] + b2d;
                v2 = v2 + (h2 - v2) * 0.5;
                const bool sp = (v2 >= 1.0);
                v2 = sp ? 0.0 : v2;
                un += sp ? ct : 0.0;
            }
            ct *= 2.0;
        }
        if (!kh) uu[n] = un;
        __syncthreads();
        if (tid < A_DIM) {
            double d0 = 0, d1 = 0, d2 = 0, d3 = 0;
            const float* w3p = W3 + tid * H_DIM;
            for (int j = 0; j < H_DIM; j += 4) {
                d0 = fma((double)w3p[j],     uu[j],     d0);
                d1 = fma((double)w3p[j + 1], uu[j + 1], d1);
                d2 = fma((double)w3p[j + 2], uu[j + 2], d2);
                d3 = fma((double)w3p[j + 3], uu[j + 3], d3);
            }
            const double v3 = (d0 + d1) + (d2 + d3) + (double)b3[tid] * (1.0 - 0x1p-16);
            out[be * A_DIM + tid] = (float)tanh(v3);
        }
        __syncthreads();
    }
}

extern "C" void kernel_launch(void* const* d_in, const int* in_sizes, int n_in,
                              void* d_out, int out_size, void* d_ws, size_t ws_size,
                              hipStream_t stream)
{
    const float* state = (const float*)d_in[0];
    const float* W1    = (const float*)d_in[1];
    const float* b1    = (const float*)d_in[2];
    const float* W2    = (const float*)d_in[3];
    const float* b2    = (const float*)d_in[4];
    const float* W3    = (const float*)d_in[5];
    const float* b3    = (const float*)d_in[6];
    float* out = (float*)d_out;

    unsigned int* gcount = (unsigned int*)d_ws;
    unsigned int* glist  = (unsigned int*)d_ws + 4;
    const unsigned int listcap =
        (ws_size > 64) ? (unsigned int)((ws_size - 16) / 4) : 0;

    hipMemsetAsync(d_ws, 0, 16, stream);   // zero flag counter (stream-ordered)

    const int B = in_sizes[0] / S_DIM;     // 131072
    const int GRID = 1024;                 // 3 resident blocks/CU (LDS-limited)
    const int nIter = B / (GRID * BT);     // 32

    snn_pers<<<GRID, 512, 0, stream>>>(state, W1, b1, W2, b2, W3, b3,
                                       out, gcount, glist, listcap, nIter);
    snn_fix<<<2048, 512, 0, stream>>>(state, W1, b1, W2, b2, W3, b3,
                                      out, gcount, glist, listcap);
}